// Round 5
// baseline (960.451 us; speedup 1.0000x reference)
//
#include <hip/hip_runtime.h>
#include <hip/hip_bf16.h>

#define NPTS 65536
#define NSAMP 16
#define CH 256
#define CNT (NPTS * NSAMP)   // 1048576
#define EPSV 1e-5f

typedef __hip_bfloat16 bf16;
typedef __attribute__((ext_vector_type(8))) short short8;
typedef __attribute__((ext_vector_type(4))) float floatx4;

__device__ __forceinline__ float b2f(bf16 v) { return __bfloat162float(v); }

// bf16 bits (as short) -> float
__device__ __forceinline__ float s2f(short v) {
    return __uint_as_float(((unsigned)(unsigned short)v) << 16);
}

__device__ __forceinline__ short f2bf_bits(float f) {
    bf16 h = __float2bfloat16(f);
    short s;
    __builtin_memcpy(&s, &h, 2);
    return s;
}

// ---------------------------------------------------------------------------
// convw: pack wq|wk|wv (f32) into Wcat[768*256] bf16
// ---------------------------------------------------------------------------
__global__ __launch_bounds__(256) void convw_kernel(
    const float* __restrict__ wq, const float* __restrict__ wk,
    const float* __restrict__ wv, bf16* __restrict__ Wcat)
{
    int e = (blockIdx.x * 256 + threadIdx.x) * 8;   // e < 196608
    const float* src = (e < 65536) ? wq : (e < 131072) ? wk : wv;
    int off = e & 65535;
    float4 f0 = *(const float4*)(src + off);
    float4 f1 = *(const float4*)(src + off + 4);
    short8 r;
    r[0] = f2bf_bits(f0.x); r[1] = f2bf_bits(f0.y);
    r[2] = f2bf_bits(f0.z); r[3] = f2bf_bits(f0.w);
    r[4] = f2bf_bits(f1.x); r[5] = f2bf_bits(f1.y);
    r[6] = f2bf_bits(f1.z); r[7] = f2bf_bits(f1.w);
    *(short8*)(Wcat + e) = r;
}

// ---------------------------------------------------------------------------
// gemm: C[65536 x 768] = x(f32) @ Wcat^T, written as xq|xk|xv bf16 slices.
// 128x128 tiles, BK=32, LDS stride 40 (pad), 4 waves each 64x64.
// ---------------------------------------------------------------------------
__global__ __launch_bounds__(256) void gemm_kernel(
    const float* __restrict__ x, const bf16* __restrict__ Wcat,
    const float* __restrict__ bq, const float* __restrict__ bk,
    const float* __restrict__ bv,
    bf16* __restrict__ xq, bf16* __restrict__ xk, bf16* __restrict__ xv)
{
    __shared__ __align__(16) bf16 As[128 * 40];
    __shared__ __align__(16) bf16 Bs[128 * 40];

    int t = threadIdx.x, lane = t & 63, wave = t >> 6;
    int m0 = blockIdx.x * 128;
    int y = blockIdx.y, n0 = y * 128;
    int srow = t >> 1, sch = t & 1;
    int m = lane & 15, q = lane >> 4;
    int wm = wave >> 1, wn = wave & 1;

    floatx4 acc[4][4];
#pragma unroll
    for (int a = 0; a < 4; a++)
#pragma unroll
        for (int b = 0; b < 4; b++) acc[a][b] = (floatx4){0.f, 0.f, 0.f, 0.f};

    for (int kk = 0; kk < 256; kk += 32) {
        const float* ap = x + (size_t)(m0 + srow) * 256 + kk + sch * 16;
        float4 a0 = *(const float4*)(ap);
        float4 a1 = *(const float4*)(ap + 4);
        float4 a2 = *(const float4*)(ap + 8);
        float4 a3 = *(const float4*)(ap + 12);
        short8 h0, h1;
        h0[0] = f2bf_bits(a0.x); h0[1] = f2bf_bits(a0.y);
        h0[2] = f2bf_bits(a0.z); h0[3] = f2bf_bits(a0.w);
        h0[4] = f2bf_bits(a1.x); h0[5] = f2bf_bits(a1.y);
        h0[6] = f2bf_bits(a1.z); h0[7] = f2bf_bits(a1.w);
        h1[0] = f2bf_bits(a2.x); h1[1] = f2bf_bits(a2.y);
        h1[2] = f2bf_bits(a2.z); h1[3] = f2bf_bits(a2.w);
        h1[4] = f2bf_bits(a3.x); h1[5] = f2bf_bits(a3.y);
        h1[6] = f2bf_bits(a3.z); h1[7] = f2bf_bits(a3.w);
        *(short8*)&As[srow * 40 + sch * 16]     = h0;
        *(short8*)&As[srow * 40 + sch * 16 + 8] = h1;
        const bf16* bp = Wcat + (size_t)(n0 + srow) * 256 + kk + sch * 16;
        *(short8*)&Bs[srow * 40 + sch * 16]     = *(const short8*)bp;
        *(short8*)&Bs[srow * 40 + sch * 16 + 8] = *(const short8*)(bp + 8);
        __syncthreads();

        short8 av[4], bvv[4];
#pragma unroll
        for (int mt = 0; mt < 4; mt++)
            av[mt] = *(const short8*)&As[(wm * 64 + mt * 16 + m) * 40 + q * 8];
#pragma unroll
        for (int nt = 0; nt < 4; nt++)
            bvv[nt] = *(const short8*)&Bs[(wn * 64 + nt * 16 + m) * 40 + q * 8];
#pragma unroll
        for (int mt = 0; mt < 4; mt++)
#pragma unroll
            for (int nt = 0; nt < 4; nt++)
                acc[mt][nt] = __builtin_amdgcn_mfma_f32_16x16x32_bf16(av[mt], bvv[nt], acc[mt][nt], 0, 0, 0);
        __syncthreads();
    }

    int z = y >> 1;
    bf16* O        = (z == 0) ? xq : (z == 1) ? xk : xv;
    const float* B = (z == 0) ? bq : (z == 1) ? bk : bv;
    int cbase = (y & 1) * 128 + wn * 64;
#pragma unroll
    for (int nt = 0; nt < 4; nt++) {
        int oc = cbase + nt * 16 + m;
        float bias = B[oc];
#pragma unroll
        for (int mt = 0; mt < 4; mt++) {
            int grow = m0 + wm * 64 + mt * 16 + q * 4;
#pragma unroll
            for (int i = 0; i < 4; i++)
                O[(size_t)(grow + i) * 256 + oc] = __float2bfloat16(acc[mt][nt][i] + bias);
        }
    }
}

// ---------------------------------------------------------------------------
// statsp: BN_p stats over p_r1 = (p[idx]-p) @ wp1^T + bp1   (3 channels)
// ---------------------------------------------------------------------------
__global__ __launch_bounds__(256) void statsp_kernel(
    const float* __restrict__ p, const int* __restrict__ idx,
    const float* __restrict__ wp1, const float* __restrict__ bp1,
    float* __restrict__ statsP)
{
    float W00 = wp1[0], W01 = wp1[1], W02 = wp1[2];
    float W10 = wp1[3], W11 = wp1[4], W12 = wp1[5];
    float W20 = wp1[6], W21 = wp1[7], W22 = wp1[8];
    float B0 = bp1[0], B1 = bp1[1], B2 = bp1[2];

    float s0 = 0, s1 = 0, s2 = 0, q0 = 0, q1 = 0, q2 = 0;
    int stride = gridDim.x * blockDim.x;
    for (int r = blockIdx.x * blockDim.x + threadIdx.x; r < CNT; r += stride) {
        int n = r >> 4;
        int i = idx[r];
        float a0 = p[3 * (size_t)i]     - p[3 * (size_t)n];
        float a1 = p[3 * (size_t)i + 1] - p[3 * (size_t)n + 1];
        float a2 = p[3 * (size_t)i + 2] - p[3 * (size_t)n + 2];
        float v0 = W00 * a0 + W01 * a1 + W02 * a2 + B0;
        float v1 = W10 * a0 + W11 * a1 + W12 * a2 + B1;
        float v2 = W20 * a0 + W21 * a1 + W22 * a2 + B2;
        s0 += v0; q0 += v0 * v0;
        s1 += v1; q1 += v1 * v1;
        s2 += v2; q2 += v2 * v2;
    }
    float v[6] = {s0, s1, s2, q0, q1, q2};
#pragma unroll
    for (int k = 0; k < 6; k++) {
        float xv = v[k];
#pragma unroll
        for (int off = 32; off > 0; off >>= 1) xv += __shfl_down(xv, off);
        if ((threadIdx.x & 63) == 0) atomicAdd(&statsP[k], xv);
    }
}

// ---------------------------------------------------------------------------
// finalize: mean/var -> scale/shift
// ---------------------------------------------------------------------------
__global__ void finalize_kernel(const float* __restrict__ stats,
                                const float* __restrict__ gamma,
                                const float* __restrict__ beta,
                                float* __restrict__ ss, int nch)
{
    int c = threadIdx.x;
    if (c < nch) {
        float inv = 1.0f / (float)CNT;
        float mean = stats[c] * inv;
        float var = stats[nch + c] * inv - mean * mean;
        float sc = gamma[c] * rsqrtf(var + EPSV);
        ss[c] = sc;
        ss[nch + c] = beta[c] - mean * sc;
    }
}

// ---------------------------------------------------------------------------
// stats1: phase 0 produces r4 = relu(BN_p(p_r1)) (global + LDS), then
// BN1 stats over w = xk[idx] - xq + p_r2 (8 ch/thread short8 gathers).
// ---------------------------------------------------------------------------
__global__ __launch_bounds__(256) void stats1_kernel(
    const int* __restrict__ idx, const float* __restrict__ p,
    const float* __restrict__ wp1, const float* __restrict__ bp1,
    const float* __restrict__ ssP, float4* __restrict__ r4,
    const bf16* __restrict__ xk, const bf16* __restrict__ xq,
    const float* __restrict__ wp2, const float* __restrict__ bp2,
    float* __restrict__ stats1)
{
    __shared__ int idxs[1024];
    __shared__ float4 r4s[1024];
    __shared__ float redS[8 * 264];
    __shared__ float redQ[8 * 264];

    int t = threadIdx.x;
    int r0 = blockIdx.x * 1024;

    // ---- phase 0: compute r4 for this block's 1024 rows ----
    {
        float W00 = wp1[0], W01 = wp1[1], W02 = wp1[2];
        float W10 = wp1[3], W11 = wp1[4], W12 = wp1[5];
        float W20 = wp1[6], W21 = wp1[7], W22 = wp1[8];
        float B0 = bp1[0], B1 = bp1[1], B2 = bp1[2];
        float sc0 = ssP[0], sc1 = ssP[1], sc2 = ssP[2];
        float sh0 = ssP[3], sh1 = ssP[4], sh2 = ssP[5];

        int4 i4 = *(const int4*)(idx + r0 + t * 4);
        int n = (r0 + t * 4) >> 4;
        float pn0 = p[3 * (size_t)n], pn1 = p[3 * (size_t)n + 1], pn2 = p[3 * (size_t)n + 2];
        int ii[4] = {i4.x, i4.y, i4.z, i4.w};
#pragma unroll
        for (int k = 0; k < 4; k++) {
            int i = ii[k];
            float a0 = p[3 * (size_t)i]     - pn0;
            float a1 = p[3 * (size_t)i + 1] - pn1;
            float a2 = p[3 * (size_t)i + 2] - pn2;
            float v0 = fmaxf(sc0 * (W00 * a0 + W01 * a1 + W02 * a2 + B0) + sh0, 0.f);
            float v1 = fmaxf(sc1 * (W10 * a0 + W11 * a1 + W12 * a2 + B1) + sh1, 0.f);
            float v2 = fmaxf(sc2 * (W20 * a0 + W21 * a1 + W22 * a2 + B2) + sh2, 0.f);
            float4 rv = make_float4(v0, v1, v2, 0.f);
            r4[r0 + t * 4 + k] = rv;
            r4s[t * 4 + k] = rv;
            idxs[t * 4 + k] = i;
        }
    }

    int sub = t & 31, rl = t >> 5, cb = sub * 8;
    float w0[8], w1[8], w2[8], bc[8];
#pragma unroll
    for (int k = 0; k < 8; k++) {
        w0[k] = wp2[3 * (cb + k)];
        w1[k] = wp2[3 * (cb + k) + 1];
        w2[k] = wp2[3 * (cb + k) + 2];
        bc[k] = bp2[cb + k];
    }
    float s8[8] = {0, 0, 0, 0, 0, 0, 0, 0};
    float q8[8] = {0, 0, 0, 0, 0, 0, 0, 0};
    __syncthreads();

#pragma unroll 4
    for (int rr = rl; rr < 1024; rr += 8) {
        int r = r0 + rr;
        int i = idxs[rr];
        float4 rv = r4s[rr];
        short8 kv = *(const short8*)(xk + (size_t)i * 256 + cb);
        short8 qv = *(const short8*)(xq + (size_t)(r >> 4) * 256 + cb);
#pragma unroll
        for (int k = 0; k < 8; k++) {
            float w = s2f(kv[k]) - s2f(qv[k]) + rv.x * w0[k] + rv.y * w1[k] + rv.z * w2[k] + bc[k];
            s8[k] += w; q8[k] += w * w;
        }
    }
#pragma unroll
    for (int k = 0; k < 8; k++) {
        redS[rl * 264 + cb + k] = s8[k];
        redQ[rl * 264 + cb + k] = q8[k];
    }
    __syncthreads();
    int c = t;
    float ts = 0, tq = 0;
#pragma unroll
    for (int sr = 0; sr < 8; sr++) {
        ts += redS[sr * 264 + c];
        tq += redQ[sr * 264 + c];
    }
    atomicAdd(&stats1[c], ts);
    atomicAdd(&stats1[256 + c], tq);
}

// ---------------------------------------------------------------------------
// stats2: y2 = relu(BN1(w)) @ ww1^T + bw1 (bf16) + BN2 stats.
// y2 stores go through LDS tile -> coalesced short8 global stores.
// ---------------------------------------------------------------------------
__global__ __launch_bounds__(256) void stats2_kernel(
    const int* __restrict__ idx, const float4* __restrict__ r4,
    const bf16* __restrict__ xk, const bf16* __restrict__ xq,
    const float* __restrict__ wp2, const float* __restrict__ bp2,
    const float* __restrict__ ss1,
    const float* __restrict__ ww1, const float* __restrict__ bw1,
    bf16* __restrict__ y2, float* __restrict__ stats2)
{
    __shared__ __align__(16) bf16 hb[64 * 264];    // h tile, stride 264
    __shared__ __align__(16) bf16 ws1[32 * 264];   // ww1 bf16, stride 264
    __shared__ __align__(16) bf16 y2s[64 * 40];    // y2 tile, stride 40
    __shared__ int idxs[1024];

    int t = threadIdx.x;
    int lane = t & 63, wave = t >> 6;
    int m = lane & 15, q = lane >> 4;
    int sub = t & 31, rl = t >> 5, cb = sub * 8;
    int r0 = blockIdx.x * 1024;

    for (int e = t; e < 8192; e += 256)
        ws1[(e >> 8) * 264 + (e & 255)] = __float2bfloat16(ww1[e]);
    for (int e = t; e < 1024; e += 256) idxs[e] = idx[r0 + e];

    float w0[8], w1[8], w2[8], bc[8], s1c[8], t1c[8];
#pragma unroll
    for (int k = 0; k < 8; k++) {
        w0[k] = wp2[3 * (cb + k)];
        w1[k] = wp2[3 * (cb + k) + 1];
        w2[k] = wp2[3 * (cb + k) + 2];
        bc[k] = bp2[cb + k];
        s1c[k] = ss1[cb + k];
        t1c[k] = ss1[256 + cb + k];
    }
    float bw0 = bw1[m], bw16 = bw1[16 + m];
    float jsum0 = 0, jsum1 = 0, jsq0 = 0, jsq1 = 0;
    __syncthreads();

    for (int it = 0; it < 16; it++) {
        int rb = r0 + it * 64;
        // phase 1: 64 rows of h into LDS
#pragma unroll 2
        for (int rr = rl; rr < 64; rr += 8) {
            int r = rb + rr;
            int i = idxs[it * 64 + rr];
            float4 rv = r4[r];
            short8 kv = *(const short8*)(xk + (size_t)i * 256 + cb);
            short8 qv = *(const short8*)(xq + (size_t)(r >> 4) * 256 + cb);
            short8 h;
#pragma unroll
            for (int k = 0; k < 8; k++) {
                float w = s2f(kv[k]) - s2f(qv[k]) + rv.x * w0[k] + rv.y * w1[k] + rv.z * w2[k] + bc[k];
                h[k] = f2bf_bits(fmaxf(s1c[k] * w + t1c[k], 0.f));
            }
            *(short8*)&hb[rr * 264 + cb] = h;
        }
        __syncthreads();
        // phase 2: wave MFMAs rows [wave*16, wave*16+16)
        floatx4 a0 = (floatx4){0.f, 0.f, 0.f, 0.f};
        floatx4 a1 = (floatx4){0.f, 0.f, 0.f, 0.f};
        const bf16* abase = hb + (wave * 16 + m) * 264 + q * 8;
#pragma unroll
        for (int k = 0; k < 8; k++) {
            short8 af = *(const short8*)(abase + k * 32);
            short8 b0 = *(const short8*)&ws1[m * 264 + k * 32 + q * 8];
            short8 b1 = *(const short8*)&ws1[(16 + m) * 264 + k * 32 + q * 8];
            a0 = __builtin_amdgcn_mfma_f32_16x16x32_bf16(af, b0, a0, 0, 0, 0);
            a1 = __builtin_amdgcn_mfma_f32_16x16x32_bf16(af, b1, a1, 0, 0, 0);
        }
        int lrow = wave * 16 + q * 4;
#pragma unroll
        for (int ii = 0; ii < 4; ii++) {
            float y0 = a0[ii] + bw0;
            float y1 = a1[ii] + bw16;
            jsum0 += y0; jsq0 += y0 * y0;
            jsum1 += y1; jsq1 += y1 * y1;
            y2s[(lrow + ii) * 40 + m]      = __float2bfloat16(y0);
            y2s[(lrow + ii) * 40 + 16 + m] = __float2bfloat16(y1);
        }
        __syncthreads();
        // coalesced copy-out: 64 rows x 32 ch
        {
            int row = t >> 2, col = (t & 3) * 8;
            short8 v = *(const short8*)&y2s[row * 40 + col];
            *(short8*)(y2 + (size_t)(rb + row) * 32 + col) = v;
        }
    }
    jsum0 += __shfl_xor(jsum0, 16); jsum0 += __shfl_xor(jsum0, 32);
    jsum1 += __shfl_xor(jsum1, 16); jsum1 += __shfl_xor(jsum1, 32);
    jsq0  += __shfl_xor(jsq0, 16);  jsq0  += __shfl_xor(jsq0, 32);
    jsq1  += __shfl_xor(jsq1, 16);  jsq1  += __shfl_xor(jsq1, 32);
    if (q == 0) {
        atomicAdd(&stats2[m], jsum0);
        atomicAdd(&stats2[16 + m], jsum1);
        atomicAdd(&stats2[32 + m], jsq0);
        atomicAdd(&stats2[48 + m], jsq1);
    }
}

// ---------------------------------------------------------------------------
// final: 16 points/block. MFMA logits, in-register softmax (shfl over quads),
// R-trick for pr2 contribution, vectorized weighted gather-sum.
// ---------------------------------------------------------------------------
__global__ __launch_bounds__(256) void final_kernel(
    const int* __restrict__ idx, const float4* __restrict__ r4,
    const bf16* __restrict__ xv,
    const float* __restrict__ wp2, const float* __restrict__ bp2,
    const bf16* __restrict__ y2, const float* __restrict__ ss2,
    const float* __restrict__ ww2, const float* __restrict__ bw2,
    float* __restrict__ out)
{
    // pool: zs (256x40 bf16 = 20480B) then reused as wsms (16 x 580 f32 = 37120B)
    __shared__ __align__(16) float pool[9280];
    bf16* zs = (bf16*)pool;
    float* wsms = pool;
    __shared__ __align__(16) bf16 ww2b[32 * 40];
    __shared__ float ss2l[64];
    __shared__ float bw2l[32];
    __shared__ int ib[256];
    __shared__ float4 r4s[256];
    __shared__ float Rs[16 * 100];

    int t = threadIdx.x;
    int base = blockIdx.x * 256;           // global row base (16 points)
    int lane = t & 63, w = t >> 6;
    int m = lane & 15, q = lane >> 4;

    // stage small tensors
    for (int e = t; e < 1024; e += 256)
        ww2b[(e >> 5) * 40 + (e & 31)] = __float2bfloat16(ww2[e]);
    if (t < 64) ss2l[t] = ss2[t];
    if (t < 32) bw2l[t] = bw2[t];
    ib[t] = idx[base + t];
    r4s[t] = r4[base + t];
    // load y2 row t (32 bf16)
    const bf16* yrow = y2 + (size_t)(base + t) * 32;
    short8 yv[4];
#pragma unroll
    for (int g = 0; g < 4; g++) yv[g] = *(const short8*)(yrow + g * 8);
    __syncthreads();

    // z = relu(bn2(y2)) -> zs (bf16, stride 40)
#pragma unroll
    for (int g = 0; g < 4; g++) {
        short8 h;
#pragma unroll
        for (int k = 0; k < 8; k++) {
            int u = g * 8 + k;
            h[k] = f2bf_bits(fmaxf(ss2l[u] * s2f(yv[g][k]) + ss2l[32 + u], 0.f));
        }
        *(short8*)&zs[t * 40 + g * 8] = h;
    }
    __syncthreads();

    // logits via MFMA: wave w handles rows w*64..w*64+63 (points w*4..w*4+3)
    short8 bf[2];
    bf[0] = *(const short8*)&ww2b[m * 40 + q * 8];
    bf[1] = *(const short8*)&ww2b[(16 + m) * 40 + q * 8];
    floatx4 acc[4][2];
#pragma unroll
    for (int mt = 0; mt < 4; mt++) {
        short8 af = *(const short8*)&zs[(w * 64 + mt * 16 + m) * 40 + q * 8];
#pragma unroll
        for (int nt = 0; nt < 2; nt++) {
            acc[mt][nt] = (floatx4){0.f, 0.f, 0.f, 0.f};
            acc[mt][nt] = __builtin_amdgcn_mfma_f32_16x16x32_bf16(af, bf[nt], acc[mt][nt], 0, 0, 0);
        }
    }
    __syncthreads();   // all zs reads done; pool may be rewritten as wsms

    // softmax over the 16 neighbors of each point, per column j; R computation
#pragma unroll
    for (int mt = 0; mt < 4; mt++) {
        int pnt = w * 4 + mt;
#pragma unroll
        for (int nt = 0; nt < 2; nt++) {
            float bias = bw2l[nt * 16 + m];
            float v0 = acc[mt][nt][0] + bias;
            float v1 = acc[mt][nt][1] + bias;
            float v2 = acc[mt][nt][2] + bias;
            float v3 = acc[mt][nt][3] + bias;
            float mx = fmaxf(fmaxf(v0, v1), fmaxf(v2, v3));
            mx = fmaxf(mx, __shfl_xor(mx, 16));
            mx = fmaxf(mx, __shfl_xor(mx, 32));
            float e0 = __expf(v0 - mx), e1 = __expf(v1 - mx);
            float e2 = __expf(v2 - mx), e3 = __expf(v3 - mx);
            float s = e0 + e1 + e2 + e3;
            s += __shfl_xor(s, 16);
            s += __shfl_xor(s, 32);
            float inv = 1.f / s;
            float wv0 = e0 * inv, wv1 = e1 * inv, wv2 = e2 * inv, wv3 = e3 * inv;
            // R partial over this lane's 4 rows
            float4 r0 = r4s[pnt * 16 + q * 4 + 0];
            float4 r1 = r4s[pnt * 16 + q * 4 + 1];
            float4 r2 = r4s[pnt * 16 + q * 4 + 2];
            float4 r3 = r4s[pnt * 16 + q * 4 + 3];
            float fx = wv0 * r0.x + wv1 * r1.x + wv2 * r2.x + wv3 * r3.x;
            float fy = wv0 * r0.y + wv1 * r1.y + wv2 * r2.y + wv3 * r3.y;
            float fz = wv0 * r0.z + wv1 * r1.z + wv2 * r2.z + wv3 * r3.z;
            fx += __shfl_xor(fx, 16); fx += __shfl_xor(fx, 32);
            fy += __shfl_xor(fy, 16); fy += __shfl_xor(fy, 32);
            fz += __shfl_xor(fz, 16); fz += __shfl_xor(fz, 32);
            int j = nt * 16 + m;
            wsms[pnt * 580 + (q * 4 + 0) * 36 + j] = wv0;
            wsms[pnt * 580 + (q * 4 + 1) * 36 + j] = wv1;
            wsms[pnt * 580 + (q * 4 + 2) * 36 + j] = wv2;
            wsms[pnt * 580 + (q * 4 + 3) * 36 + j] = wv3;
            if (q == 0) {
                Rs[pnt * 100 + j * 3 + 0] = fx;
                Rs[pnt * 100 + j * 3 + 1] = fy;
                Rs[pnt * 100 + j * 3 + 2] = fz;
            }
        }
    }
    __syncthreads();

    // phase D: thread = (point, 16-channel chunk)
    int pnt = t >> 4;
    int ch = (t & 15) * 16;
    int jb = ((t & 15) & 1) * 16;
    float accd[16];
#pragma unroll
    for (int k = 0; k < 16; k++) {
        int c = ch + k, j = jb + k;
        float Rx = Rs[pnt * 100 + j * 3 + 0];
        float Ry = Rs[pnt * 100 + j * 3 + 1];
        float Rz = Rs[pnt * 100 + j * 3 + 2];
        accd[k] = Rx * wp2[3 * c] + Ry * wp2[3 * c + 1] + Rz * wp2[3 * c + 2] + bp2[c];
    }
#pragma unroll 4
    for (int s = 0; s < 16; s++) {
        int i = ib[pnt * 16 + s];
        const bf16* vr = xv + (size_t)i * 256 + ch;
        short8 x0 = *(const short8*)vr;
        short8 x1 = *(const short8*)(vr + 8);
        const float* wrow = &wsms[pnt * 580 + s * 36 + jb];
#pragma unroll
        for (int k = 0; k < 8; k++) accd[k] += s2f(x0[k]) * wrow[k];
#pragma unroll
        for (int k = 0; k < 8; k++) accd[8 + k] += s2f(x1[k]) * wrow[8 + k];
    }
    float* op = out + (size_t)(blockIdx.x * 16 + pnt) * 256 + ch;
#pragma unroll
    for (int g = 0; g < 4; g++)
        *(float4*)(op + g * 4) = make_float4(accd[g * 4], accd[g * 4 + 1], accd[g * 4 + 2], accd[g * 4 + 3]);
}

// ---------------------------------------------------------------------------
extern "C" void kernel_launch(void* const* d_in, const int* in_sizes, int n_in,
                              void* d_out, int out_size, void* d_ws, size_t ws_size,
                              hipStream_t stream) {
    (void)in_sizes; (void)n_in; (void)out_size; (void)ws_size;

    const float* p   = (const float*)d_in[0];
    const float* x   = (const float*)d_in[1];
    const int*   idx = (const int*)d_in[2];
    const float* wq  = (const float*)d_in[3];  const float* bq  = (const float*)d_in[4];
    const float* wk  = (const float*)d_in[5];  const float* bk  = (const float*)d_in[6];
    const float* wv  = (const float*)d_in[7];  const float* bv  = (const float*)d_in[8];
    const float* wp1 = (const float*)d_in[9];  const float* bp1 = (const float*)d_in[10];
    const float* gp  = (const float*)d_in[11]; const float* btp = (const float*)d_in[12];
    const float* wp2 = (const float*)d_in[13]; const float* bp2 = (const float*)d_in[14];
    const float* g1  = (const float*)d_in[15]; const float* b1  = (const float*)d_in[16];
    const float* ww1 = (const float*)d_in[17]; const float* bw1 = (const float*)d_in[18];
    const float* g2  = (const float*)d_in[19]; const float* b2  = (const float*)d_in[20];
    const float* ww2 = (const float*)d_in[21]; const float* bw2 = (const float*)d_in[22];
    float* out = (float*)d_out;

    float* fws    = (float*)d_ws;
    float* statsP = fws;            // 6  (8 slots)
    float* ssP    = fws + 8;        // 6  (8 slots)
    float* stats1 = fws + 16;       // 512
    float* ss1    = fws + 528;      // 512
    float* stats2 = fws + 1040;     // 64
    float* ss2    = fws + 1104;     // 64
    bf16* Wcat = (bf16*)((char*)d_ws + 8192);          // 768*256 bf16
    bf16* xq = (bf16*)((char*)d_ws + 401408);
    bf16* xk = xq + (size_t)NPTS * CH;
    bf16* xv = xk + (size_t)NPTS * CH;
    bf16* y2 = xv + (size_t)NPTS * CH;                 // CNT*32 bf16
    float4* r4 = (float4*)(y2 + (size_t)CNT * 32);     // CNT float4

    hipMemsetAsync(d_ws, 0, 8192, stream);

    convw_kernel<<<96, 256, 0, stream>>>(wq, wk, wv, Wcat);
    gemm_kernel<<<dim3(512, 6), 256, 0, stream>>>(x, Wcat, bq, bk, bv, xq, xk, xv);
    statsp_kernel<<<1024, 256, 0, stream>>>(p, idx, wp1, bp1, statsP);
    finalize_kernel<<<1, 256, 0, stream>>>(statsP, gp, btp, ssP, 3);
    stats1_kernel<<<1024, 256, 0, stream>>>(idx, p, wp1, bp1, ssP, r4, xk, xq, wp2, bp2, stats1);
    finalize_kernel<<<1, 256, 0, stream>>>(stats1, g1, b1, ss1, 256);
    stats2_kernel<<<1024, 256, 0, stream>>>(idx, r4, xk, xq, wp2, bp2, ss1, ww1, bw1, y2, stats2);
    finalize_kernel<<<1, 256, 0, stream>>>(stats2, g2, b2, ss2, 32);
    final_kernel<<<4096, 256, 0, stream>>>(idx, r4, xv, wp2, bp2, y2, ss2, ww2, bw2, out);
}